// Round 1
// baseline (332.388 us; speedup 1.0000x reference)
//
#include <hip/hip_runtime.h>
#include <hip/hip_bf16.h>

#define BB 64
#define HH 14
#define WW 14
#define CC 32
#define NN 6272      // H*W*C
#define OO 10
#define SS 14        // slices over N
#define NS 448       // N/SS (multiple of 32 so chunk bases are c-aligned)
#define TPB 256
#define EPSF 1e-9f

// workspace offsets (in floats)
#define ACC_PER_IT 21120            // B*O*33
#define OFF_ACC 0                   // 3 * 21120
#define OFF_MU  63360               // 2 * B*O*16
#define OFF_IV  83840               // 2 * B*O*16
#define OFF_BI  104320              // 2 * B*O

#define WT_STRIDE 164               // padded c-stride (4c mod 32 spread, 16B aligned)
#define RR_STRIDE 13                // [rr0..rr9, offw, offh, 0]

__global__ __launch_bounds__(TPB) void fc_pass(
    const float* __restrict__ pose, const float* __restrict__ actv,
    const float* __restrict__ wgt,
    const float* __restrict__ muIn, const float* __restrict__ ivIn,
    const float* __restrict__ biIn,
    float* __restrict__ acc, int iter)
{
    __shared__ __align__(16) float wT[CC * WT_STRIDE];
    __shared__ __align__(16) float poseL[TPB * 16];
    __shared__ float rrL[TPB * RR_STRIDE];
    __shared__ float muL[OO * 16], ivL[OO * 16], biL[OO];

    const int t = threadIdx.x;
    const int s = blockIdx.x;   // slice over N
    const int b = blockIdx.y;   // batch

    // stage w into LDS, transposed to wT[c][o][k][j] = w[c][o][j][k]
    for (int idx = t; idx < CC * OO * 16; idx += TPB) {
        int c = idx / 160; int r = idx - c * 160;
        int o = r >> 4; int jk = r & 15; int j = jk >> 2; int k = jk & 3;
        wT[c * WT_STRIDE + o * 16 + k * 4 + j] = wgt[idx];
    }
    if (iter > 0) {
        for (int idx = t; idx < OO * 16; idx += TPB) {
            muL[idx] = muIn[b * OO * 16 + idx];
            ivL[idx] = ivIn[b * OO * 16 + idx];
        }
        if (t < OO) biL[t] = biIn[b * OO + t];
    }
    __syncthreads();

    const int n0 = s * NS;
    // Phase-B pair decomposition: thread t<160 owns (o,d), d=(i,k)
    const int po = t >> 4, pd = t & 15, pi = pd >> 2, pk = pd & 3;
    const int offIdx = (pd == 3) ? 10 : ((pd == 7) ? 11 : 12);
    float aS1 = 0.f, aS2 = 0.f, aS0 = 0.f;

    for (int cb = 0; cb < NS; cb += TPB) {
        const int cnt = min(TPB, NS - cb);
        // ---------------- Phase A: one thread per n ----------------
        const int n = n0 + cb + t;
        const bool valid = (t < cnt);
        float a = 0.f;
        float p[16];
        #pragma unroll
        for (int j = 0; j < 16; j++) p[j] = 0.f;
        if (valid) {
            a = actv[(size_t)b * NN + n];
            const float4* pp = (const float4*)(pose + ((size_t)b * NN + n) * 16);
            float4 q0 = pp[0], q1 = pp[1], q2 = pp[2], q3 = pp[3];
            p[0]=q0.x; p[1]=q0.y; p[2]=q0.z; p[3]=q0.w;
            p[4]=q1.x; p[5]=q1.y; p[6]=q1.z; p[7]=q1.w;
            p[8]=q2.x; p[9]=q2.y; p[10]=q2.z; p[11]=q2.w;
            p[12]=q3.x; p[13]=q3.y; p[14]=q3.z; p[15]=q3.w;
        }
        {   // stash pose row for Phase B
            float4* pl = (float4*)&poseL[t * 16];
            pl[0] = make_float4(p[0], p[1], p[2], p[3]);
            pl[1] = make_float4(p[4], p[5], p[6], p[7]);
            pl[2] = make_float4(p[8], p[9], p[10], p[11]);
            pl[3] = make_float4(p[12], p[13], p[14], p[15]);
        }
        const int cch = n & 31;
        const int hw = n >> 5;
        const int wi = hw % WW, hi = hw / WW;
        const float offw = (wi + 0.5f) * (1.0f / WW);
        const float offh = (hi + 0.5f) * (1.0f / HH);

        if (iter == 0) {
            const float ra = a * 0.1f;   // rr = 1/O uniform
            #pragma unroll
            for (int o = 0; o < OO; o++) rrL[t * RR_STRIDE + o] = ra;
        } else {
            const float* wb = &wT[cch * WT_STRIDE];
            float m = -1e30f, sum = 0.f;
            for (int o = 0; o < OO; o++) {
                float sq = 0.f;
                #pragma unroll
                for (int dd = 0; dd < 16; dd++) {
                    const int ii = dd >> 2, kk = dd & 3;
                    float v = p[ii*4+0] * wb[o*16 + kk*4 + 0]
                            + p[ii*4+1] * wb[o*16 + kk*4 + 1]
                            + p[ii*4+2] * wb[o*16 + kk*4 + 2]
                            + p[ii*4+3] * wb[o*16 + kk*4 + 3];
                    if (dd == 3) v += offw;
                    if (dd == 7) v += offh;
                    const float dm = v - muL[o*16 + dd];
                    sq = fmaf(dm * dm, ivL[o*16 + dd], sq);
                }
                const float lg = biL[o] - 0.5f * sq;
                rrL[t * RR_STRIDE + o] = lg;     // stash logit
                const float mn = fmaxf(m, lg);   // online softmax
                sum = sum * __expf(m - mn) + __expf(lg - mn);
                m = mn;
            }
            const float inv = a / sum;
            for (int o = 0; o < OO; o++) {
                rrL[t * RR_STRIDE + o] = __expf(rrL[t * RR_STRIDE + o] - m) * inv;
            }
        }
        rrL[t * RR_STRIDE + 10] = offw;
        rrL[t * RR_STRIDE + 11] = offh;
        rrL[t * RR_STRIDE + 12] = 0.f;
        __syncthreads();

        // ---------------- Phase B: thread = (o,d) pair, sweep n ----------------
        if (t < 160) {
            for (int cc = 0; cc < CC; cc++) {   // hoist w per channel
                const float4 wv = *(const float4*)&wT[cc * WT_STRIDE + po * 16 + pk * 4];
                for (int nl = cc; nl < cnt; nl += CC) {   // chunk base ≡ 0 mod 32
                    const float rr = rrL[nl * RR_STRIDE + po];
                    const float4 pv = *(const float4*)&poseL[nl * 16 + pi * 4];
                    float v = fmaf(pv.x, wv.x, fmaf(pv.y, wv.y,
                              fmaf(pv.z, wv.z, pv.w * wv.w)));
                    v += rrL[nl * RR_STRIDE + offIdx];   // coord offset (0 for most d)
                    aS1 = fmaf(rr, v, aS1);
                    aS2 = fmaf(rr * v, v, aS2);
                    if (pd == 0) aS0 += rr;
                }
            }
        }
        __syncthreads();
    }

    if (t < 160) {
        float* ab = acc + ((size_t)b * OO + po) * 33;
        atomicAdd(&ab[pd], aS1);
        atomicAdd(&ab[16 + pd], aS2);
        if (pd == 0) atomicAdd(&ab[32], aS0);
    }
}

__global__ __launch_bounds__(256) void fc_stats(
    const float* __restrict__ acc, const float* __restrict__ beta_a,
    const float* __restrict__ beta_u,
    float* __restrict__ muOut, float* __restrict__ ivOut, float* __restrict__ biOut,
    float* __restrict__ out, float inv_temp, int final_it)
{
    const int t = threadIdx.x;
    const int b = blockIdx.x;
    if (t >= 160) return;
    const int o = t >> 4, d = t & 15;
    const float* ab = acc + ((size_t)b * OO + o) * 33;
    const float S1 = ab[d], S2 = ab[16 + d], S0 = ab[32];
    const float rs = S0 + EPSF;
    const float mu = S1 / rs;
    float vraw = fmaf(mu * mu, S0, fmaf(-2.f * mu, S1, S2));
    vraw = fmaxf(vraw, 0.f);
    const float var = vraw / rs + EPSF;
    const float lv = __logf(var);
    float sv = lv;
    #pragma unroll
    for (int off = 8; off >= 1; off >>= 1) sv += __shfl_xor(sv, off, 16);
    const float cost = rs * fmaf(0.5f, sv, 16.f * beta_u[o]);
    const float av = 1.f / (1.f + __expf(-inv_temp * (beta_a[o] - cost)));
    if (!final_it) {
        muOut[((size_t)b * OO + o) * 16 + d] = mu;
        ivOut[((size_t)b * OO + o) * 16 + d] = 1.f / var;
        if (d == 0) biOut[b * OO + o] = __logf(av + EPSF) - 0.5f * sv;
    } else {
        out[((size_t)b * OO + o) * 16 + d] = mu;               // pose_out (B,O,16)
        if (d == 0) out[BB * OO * 16 + b * OO + o] = av;       // act_out (B,O)
    }
}

extern "C" void kernel_launch(void* const* d_in, const int* in_sizes, int n_in,
                              void* d_out, int out_size, void* d_ws, size_t ws_size,
                              hipStream_t stream) {
    const float* pose   = (const float*)d_in[0];
    const float* actv   = (const float*)d_in[1];
    const float* wgt    = (const float*)d_in[2];
    const float* beta_a = (const float*)d_in[3];
    const float* beta_u = (const float*)d_in[4];
    float* out = (float*)d_out;
    float* ws  = (float*)d_ws;

    hipMemsetAsync(ws + OFF_ACC, 0, (size_t)3 * ACC_PER_IT * sizeof(float), stream);

    float* acc0 = ws + OFF_ACC;
    float* acc1 = ws + OFF_ACC + ACC_PER_IT;
    float* acc2 = ws + OFF_ACC + 2 * ACC_PER_IT;
    float* mu0 = ws + OFF_MU;            float* mu1 = ws + OFF_MU + 10240;
    float* iv0 = ws + OFF_IV;            float* iv1 = ws + OFF_IV + 10240;
    float* bi0 = ws + OFF_BI;            float* bi1 = ws + OFF_BI + 640;

    dim3 pgrid(SS, BB), pblk(TPB);
    fc_pass<<<pgrid, pblk, 0, stream>>>(pose, actv, wgt, nullptr, nullptr, nullptr, acc0, 0);
    fc_stats<<<BB, 256, 0, stream>>>(acc0, beta_a, beta_u, mu0, iv0, bi0, out, 1.0f, 0);
    fc_pass<<<pgrid, pblk, 0, stream>>>(pose, actv, wgt, mu0, iv0, bi0, acc1, 1);
    fc_stats<<<BB, 256, 0, stream>>>(acc1, beta_a, beta_u, mu1, iv1, bi1, out, 2.0f, 0);
    fc_pass<<<pgrid, pblk, 0, stream>>>(pose, actv, wgt, mu1, iv1, bi1, acc2, 2);
    fc_stats<<<BB, 256, 0, stream>>>(acc2, beta_a, beta_u, nullptr, nullptr, nullptr, out, 3.0f, 1);
}

// Round 2
// 248.317 us; speedup vs baseline: 1.3386x; 1.3386x over previous
//
#include <hip/hip_runtime.h>
#include <hip/hip_bf16.h>

#define BB 64
#define HH 14
#define WW 14
#define NN 6272      // H*W*C
#define OO 10
#define SSL 14       // slices over N (grid.x); 448 n per block
#define NSTEP 14     // n-steps per block (NSTEP*32 = 448)
#define TPB 320      // 32 c  x  10 o
#define EPSF 1e-9f

// workspace offsets (floats)
#define ACC_PER_IT 21120            // B*O*33
#define OFF_ACC 0                   // 3 * 21120
#define OFF_MU  63360               // 2 * B*O*16
#define OFF_IV  83840               // 2 * B*O*16
#define OFF_BI  104320              // 2 * B*O

// Thread (c,o) owns channel c = t&31 and output capsule o = t>>5 for the
// whole kernel: w[c,o], mu[o], iv[o], bias[o] and the S1/S2/S0 accumulators
// all live in registers. Only the 10 per-n logits round-trip through LDS
// (stride 11 -> conflict-free; double-buffered -> one barrier per step).
__global__ __launch_bounds__(TPB) void fc_pass(
    const float* __restrict__ pose, const float* __restrict__ actv,
    const float* __restrict__ wgt,
    const float* __restrict__ muIn, const float* __restrict__ ivIn,
    const float* __restrict__ biIn,
    float* __restrict__ acc, int iter)
{
    __shared__ float logitL[2][32 * 11];

    const int t = threadIdx.x;
    const int c = t & 31;
    const int o = t >> 5;           // 0..9
    const int ss = blockIdx.x;
    const int b  = blockIdx.y;

    // W[c][o] 4x4, wr[j*4+k]
    float wr[16];
    {
        const float4* wp = (const float4*)(wgt + ((c * OO + o) << 4));
        float4 a0 = wp[0], a1 = wp[1], a2 = wp[2], a3 = wp[3];
        wr[0]=a0.x; wr[1]=a0.y; wr[2]=a0.z; wr[3]=a0.w;
        wr[4]=a1.x; wr[5]=a1.y; wr[6]=a1.z; wr[7]=a1.w;
        wr[8]=a2.x; wr[9]=a2.y; wr[10]=a2.z; wr[11]=a2.w;
        wr[12]=a3.x; wr[13]=a3.y; wr[14]=a3.z; wr[15]=a3.w;
    }

    float mu[16], iv[16], bias = 0.f;
    if (iter > 0) {
        const float4* mp = (const float4*)(muIn + (((size_t)b * OO + o) << 4));
        const float4* vp = (const float4*)(ivIn + (((size_t)b * OO + o) << 4));
        float4 m0=mp[0], m1=mp[1], m2=mp[2], m3=mp[3];
        mu[0]=m0.x; mu[1]=m0.y; mu[2]=m0.z; mu[3]=m0.w;
        mu[4]=m1.x; mu[5]=m1.y; mu[6]=m1.z; mu[7]=m1.w;
        mu[8]=m2.x; mu[9]=m2.y; mu[10]=m2.z; mu[11]=m2.w;
        mu[12]=m3.x; mu[13]=m3.y; mu[14]=m3.z; mu[15]=m3.w;
        float4 v0=vp[0], v1=vp[1], v2=vp[2], v3=vp[3];
        iv[0]=v0.x; iv[1]=v0.y; iv[2]=v0.z; iv[3]=v0.w;
        iv[4]=v1.x; iv[5]=v1.y; iv[6]=v1.z; iv[7]=v1.w;
        iv[8]=v2.x; iv[9]=v2.y; iv[10]=v2.z; iv[11]=v2.w;
        iv[12]=v3.x; iv[13]=v3.y; iv[14]=v3.z; iv[15]=v3.w;
        bias = biIn[b * OO + o];
    }

    float S1[16], S2[16], S0 = 0.f;
    #pragma unroll
    for (int d = 0; d < 16; d++) { S1[d] = 0.f; S2[d] = 0.f; }

    const size_t baseN = (size_t)b * NN + ss * (NSTEP * 32);
    const float offh = (ss + 0.5f) * (1.0f / HH);   // hi == ss for all n in block

    for (int s = 0; s < NSTEP; s++) {
        const float offw = (s + 0.5f) * (1.0f / WW); // wi == s
        const int n = s * 32 + c;

        float p[16];
        {
            const float4* pp = (const float4*)(pose + (baseN + n) * 16);
            float4 q0 = pp[0], q1 = pp[1], q2 = pp[2], q3 = pp[3];
            p[0]=q0.x; p[1]=q0.y; p[2]=q0.z; p[3]=q0.w;
            p[4]=q1.x; p[5]=q1.y; p[6]=q1.z; p[7]=q1.w;
            p[8]=q2.x; p[9]=q2.y; p[10]=q2.z; p[11]=q2.w;
            p[12]=q3.x; p[13]=q3.y; p[14]=q3.z; p[15]=q3.w;
        }
        const float a = actv[baseN + n];

        // votes for this thread's o (coord-addition folded in)
        float v[16];
        #pragma unroll
        for (int ii = 0; ii < 4; ii++) {
            #pragma unroll
            for (int kk = 0; kk < 4; kk++) {
                float vv = fmaf(p[ii*4+0], wr[0*4+kk],
                           fmaf(p[ii*4+1], wr[1*4+kk],
                           fmaf(p[ii*4+2], wr[2*4+kk],
                                p[ii*4+3] * wr[3*4+kk])));
                if (ii == 0 && kk == 3) vv += offw;
                if (ii == 1 && kk == 3) vv += offh;
                v[ii*4+kk] = vv;
            }
        }

        float rr;
        if (iter > 0) {
            float sq = 0.f;
            #pragma unroll
            for (int d = 0; d < 16; d++) {
                const float dm = v[d] - mu[d];
                sq = fmaf(dm * dm, iv[d], sq);
            }
            const float lg = bias - 0.5f * sq;
            logitL[s & 1][c * 11 + o] = lg;
            __syncthreads();
            float m = -1e30f, sum = 0.f;
            #pragma unroll
            for (int o2 = 0; o2 < OO; o2++) {
                const float lg2 = logitL[s & 1][c * 11 + o2];
                const float mn = fmaxf(m, lg2);
                sum = sum * __expf(m - mn) + __expf(lg2 - mn);
                m = mn;
            }
            rr = __expf(lg - m) * a / sum;
        } else {
            rr = 0.1f * a;     // uniform routing, scaled by activation
        }

        #pragma unroll
        for (int d = 0; d < 16; d++) {
            const float rv = rr * v[d];
            S1[d] += rv;
            S2[d] = fmaf(rv, v[d], S2[d]);
        }
        S0 += rr;
    }

    // butterfly-reduce each of the 33 sums over the 32 c-lanes of this o
    float* ab = acc + ((size_t)b * OO + o) * 33;
    float myred = 0.f;
    #pragma unroll
    for (int k = 0; k < 32; k++) {
        float tot = (k < 16) ? S1[k] : S2[k - 16];
        #pragma unroll
        for (int msk = 16; msk >= 1; msk >>= 1)
            tot += __shfl_xor(tot, msk, 32);
        if (c == k) myred = tot;
    }
    {
        float tot = S0;
        #pragma unroll
        for (int msk = 16; msk >= 1; msk >>= 1)
            tot += __shfl_xor(tot, msk, 32);
        if (c == 0) atomicAdd(&ab[32], tot);
    }
    atomicAdd(&ab[c], myred);
}

__global__ __launch_bounds__(256) void fc_stats(
    const float* __restrict__ acc, const float* __restrict__ beta_a,
    const float* __restrict__ beta_u,
    float* __restrict__ muOut, float* __restrict__ ivOut, float* __restrict__ biOut,
    float* __restrict__ out, float inv_temp, int final_it)
{
    const int t = threadIdx.x;
    const int b = blockIdx.x;
    if (t >= 160) return;
    const int o = t >> 4, d = t & 15;
    const float* ab = acc + ((size_t)b * OO + o) * 33;
    const float S1 = ab[d], S2 = ab[16 + d], S0 = ab[32];
    const float rs = S0 + EPSF;
    const float mu = S1 / rs;
    float vraw = fmaf(mu * mu, S0, fmaf(-2.f * mu, S1, S2));
    vraw = fmaxf(vraw, 0.f);
    const float var = vraw / rs + EPSF;
    const float lv = __logf(var);
    float sv = lv;
    #pragma unroll
    for (int off = 8; off >= 1; off >>= 1) sv += __shfl_xor(sv, off, 16);
    const float cost = rs * fmaf(0.5f, sv, 16.f * beta_u[o]);
    const float av = 1.f / (1.f + __expf(-inv_temp * (beta_a[o] - cost)));
    if (!final_it) {
        muOut[((size_t)b * OO + o) * 16 + d] = mu;
        ivOut[((size_t)b * OO + o) * 16 + d] = 1.f / var;
        if (d == 0) biOut[b * OO + o] = __logf(av + EPSF) - 0.5f * sv;
    } else {
        out[((size_t)b * OO + o) * 16 + d] = mu;               // pose_out (B,O,16)
        if (d == 0) out[BB * OO * 16 + b * OO + o] = av;       // act_out (B,O)
    }
}

extern "C" void kernel_launch(void* const* d_in, const int* in_sizes, int n_in,
                              void* d_out, int out_size, void* d_ws, size_t ws_size,
                              hipStream_t stream) {
    const float* pose   = (const float*)d_in[0];
    const float* actv   = (const float*)d_in[1];
    const float* wgt    = (const float*)d_in[2];
    const float* beta_a = (const float*)d_in[3];
    const float* beta_u = (const float*)d_in[4];
    float* out = (float*)d_out;
    float* ws  = (float*)d_ws;

    hipMemsetAsync(ws + OFF_ACC, 0, (size_t)3 * ACC_PER_IT * sizeof(float), stream);

    float* acc0 = ws + OFF_ACC;
    float* acc1 = ws + OFF_ACC + ACC_PER_IT;
    float* acc2 = ws + OFF_ACC + 2 * ACC_PER_IT;
    float* mu0 = ws + OFF_MU;            float* mu1 = ws + OFF_MU + 10240;
    float* iv0 = ws + OFF_IV;            float* iv1 = ws + OFF_IV + 10240;
    float* bi0 = ws + OFF_BI;            float* bi1 = ws + OFF_BI + 640;

    dim3 pgrid(SSL, BB), pblk(TPB);
    fc_pass<<<pgrid, pblk, 0, stream>>>(pose, actv, wgt, nullptr, nullptr, nullptr, acc0, 0);
    fc_stats<<<BB, 256, 0, stream>>>(acc0, beta_a, beta_u, mu0, iv0, bi0, out, 1.0f, 0);
    fc_pass<<<pgrid, pblk, 0, stream>>>(pose, actv, wgt, mu0, iv0, bi0, acc1, 1);
    fc_stats<<<BB, 256, 0, stream>>>(acc1, beta_a, beta_u, mu1, iv1, bi1, out, 2.0f, 0);
    fc_pass<<<pgrid, pblk, 0, stream>>>(pose, actv, wgt, mu1, iv1, bi1, acc2, 2);
    fc_stats<<<BB, 256, 0, stream>>>(acc2, beta_a, beta_u, nullptr, nullptr, nullptr, out, 3.0f, 1);
}

// Round 3
// 235.781 us; speedup vs baseline: 1.4097x; 1.0532x over previous
//
#include <hip/hip_runtime.h>
#include <hip/hip_bf16.h>

#define BB 64
#define HH 14
#define WW 14
#define NN 6272      // H*W*C
#define OO 10
#define SSL 14       // slices over N (grid.x); 448 n per block
#define NSTEP 14     // n-steps per block (NSTEP*32 = 448)
#define TPB 320      // 32 c  x  10 o
#define EPSF 1e-9f

// workspace offsets (floats)
#define ACC_PER_IT 21120            // B*O*33
#define OFF_ACC 0                   // 3 * 21120
#define OFF_MU  63360               // 2 * B*O*16
#define OFF_IV  83840               // 2 * B*O*16
#define OFF_BI  104320              // 2 * B*O

// Thread (c,o) owns channel c = t&31 and output capsule o = t>>5 for the
// whole kernel: w[c,o], mu[o], iv[o], bias[o] and the S1/S2/S0 accumulators
// all live in registers. Only the 10 per-n logits round-trip through LDS
// (stride 11 -> conflict-free; double-buffered -> one barrier per step).
// __launch_bounds__(320,3): VGPR cap 170 -- without this the compiler
// targets 8 waves/EU, caps at 64 VGPRs and AGPR-shuffles ~50 live values
// in the inner loop (R2: VALUBusy 35%, 75us/pass).
__global__ __launch_bounds__(TPB, 3) void fc_pass(
    const float* __restrict__ pose, const float* __restrict__ actv,
    const float* __restrict__ wgt,
    const float* __restrict__ muIn, const float* __restrict__ ivIn,
    const float* __restrict__ biIn,
    float* __restrict__ acc, int iter)
{
    __shared__ float logitL[2][32 * 11];

    const int t = threadIdx.x;
    const int c = t & 31;
    const int o = t >> 5;           // 0..9
    const int ss = blockIdx.x;
    const int b  = blockIdx.y;

    // W[c][o] 4x4, wr[j*4+k]
    float wr[16];
    {
        const float4* wp = (const float4*)(wgt + ((c * OO + o) << 4));
        float4 a0 = wp[0], a1 = wp[1], a2 = wp[2], a3 = wp[3];
        wr[0]=a0.x; wr[1]=a0.y; wr[2]=a0.z; wr[3]=a0.w;
        wr[4]=a1.x; wr[5]=a1.y; wr[6]=a1.z; wr[7]=a1.w;
        wr[8]=a2.x; wr[9]=a2.y; wr[10]=a2.z; wr[11]=a2.w;
        wr[12]=a3.x; wr[13]=a3.y; wr[14]=a3.z; wr[15]=a3.w;
    }

    float mu[16], iv[16], bias = 0.f;
    if (iter > 0) {
        const float4* mp = (const float4*)(muIn + (((size_t)b * OO + o) << 4));
        const float4* vp = (const float4*)(ivIn + (((size_t)b * OO + o) << 4));
        float4 m0=mp[0], m1=mp[1], m2=mp[2], m3=mp[3];
        mu[0]=m0.x; mu[1]=m0.y; mu[2]=m0.z; mu[3]=m0.w;
        mu[4]=m1.x; mu[5]=m1.y; mu[6]=m1.z; mu[7]=m1.w;
        mu[8]=m2.x; mu[9]=m2.y; mu[10]=m2.z; mu[11]=m2.w;
        mu[12]=m3.x; mu[13]=m3.y; mu[14]=m3.z; mu[15]=m3.w;
        float4 v0=vp[0], v1=vp[1], v2=vp[2], v3=vp[3];
        iv[0]=v0.x; iv[1]=v0.y; iv[2]=v0.z; iv[3]=v0.w;
        iv[4]=v1.x; iv[5]=v1.y; iv[6]=v1.z; iv[7]=v1.w;
        iv[8]=v2.x; iv[9]=v2.y; iv[10]=v2.z; iv[11]=v2.w;
        iv[12]=v3.x; iv[13]=v3.y; iv[14]=v3.z; iv[15]=v3.w;
        bias = biIn[b * OO + o];
    }

    float S1[16], S2[16], S0 = 0.f;
    #pragma unroll
    for (int d = 0; d < 16; d++) { S1[d] = 0.f; S2[d] = 0.f; }

    const size_t baseN = (size_t)b * NN + ss * (NSTEP * 32);
    const float offh = (ss + 0.5f) * (1.0f / HH);   // hi == ss for all n in block

    for (int s = 0; s < NSTEP; s++) {
        const float offw = (s + 0.5f) * (1.0f / WW); // wi == s
        const int n = s * 32 + c;

        // issue all global loads for this step up front
        const float4* pp = (const float4*)(pose + (baseN + n) * 16);
        float4 q0 = pp[0], q1 = pp[1], q2 = pp[2], q3 = pp[3];
        const float a = actv[baseN + n];

        float p[16];
        p[0]=q0.x; p[1]=q0.y; p[2]=q0.z; p[3]=q0.w;
        p[4]=q1.x; p[5]=q1.y; p[6]=q1.z; p[7]=q1.w;
        p[8]=q2.x; p[9]=q2.y; p[10]=q2.z; p[11]=q2.w;
        p[12]=q3.x; p[13]=q3.y; p[14]=q3.z; p[15]=q3.w;

        // votes for this thread's o (coord-addition folded in)
        float v[16];
        #pragma unroll
        for (int ii = 0; ii < 4; ii++) {
            #pragma unroll
            for (int kk = 0; kk < 4; kk++) {
                float vv = fmaf(p[ii*4+0], wr[0*4+kk],
                           fmaf(p[ii*4+1], wr[1*4+kk],
                           fmaf(p[ii*4+2], wr[2*4+kk],
                                p[ii*4+3] * wr[3*4+kk])));
                if (ii == 0 && kk == 3) vv += offw;
                if (ii == 1 && kk == 3) vv += offh;
                v[ii*4+kk] = vv;
            }
        }

        float rr;
        if (iter > 0) {
            float sq = 0.f;
            #pragma unroll
            for (int d = 0; d < 16; d++) {
                const float dm = v[d] - mu[d];
                sq = fmaf(dm * dm, iv[d], sq);
            }
            const float lg = bias - 0.5f * sq;
            logitL[s & 1][c * 11 + o] = lg;
            __syncthreads();
            // two-pass softmax over the 10 logits (register-resident)
            float lgs[OO];
            #pragma unroll
            for (int o2 = 0; o2 < OO; o2++) lgs[o2] = logitL[s & 1][c * 11 + o2];
            float m = lgs[0];
            #pragma unroll
            for (int o2 = 1; o2 < OO; o2++) m = fmaxf(m, lgs[o2]);
            float sum = 0.f;
            #pragma unroll
            for (int o2 = 0; o2 < OO; o2++) sum += __expf(lgs[o2] - m);
            rr = __expf(lg - m) * a / sum;
        } else {
            rr = 0.1f * a;     // uniform routing, scaled by activation
        }

        #pragma unroll
        for (int d = 0; d < 16; d++) {
            const float rv = rr * v[d];
            S1[d] += rv;
            S2[d] = fmaf(rv, v[d], S2[d]);
        }
        S0 += rr;
    }

    // butterfly-reduce each of the 33 sums over the 32 c-lanes of this o
    float* ab = acc + ((size_t)b * OO + o) * 33;
    float myred = 0.f;
    #pragma unroll
    for (int k = 0; k < 32; k++) {
        float tot = (k < 16) ? S1[k] : S2[k - 16];
        #pragma unroll
        for (int msk = 16; msk >= 1; msk >>= 1)
            tot += __shfl_xor(tot, msk, 32);
        if (c == k) myred = tot;
    }
    {
        float tot = S0;
        #pragma unroll
        for (int msk = 16; msk >= 1; msk >>= 1)
            tot += __shfl_xor(tot, msk, 32);
        if (c == 0) atomicAdd(&ab[32], tot);
    }
    atomicAdd(&ab[c], myred);
}

__global__ __launch_bounds__(256) void fc_stats(
    const float* __restrict__ acc, const float* __restrict__ beta_a,
    const float* __restrict__ beta_u,
    float* __restrict__ muOut, float* __restrict__ ivOut, float* __restrict__ biOut,
    float* __restrict__ out, float inv_temp, int final_it)
{
    const int t = threadIdx.x;
    const int b = blockIdx.x;
    if (t >= 160) return;
    const int o = t >> 4, d = t & 15;
    const float* ab = acc + ((size_t)b * OO + o) * 33;
    const float S1 = ab[d], S2 = ab[16 + d], S0 = ab[32];
    const float rs = S0 + EPSF;
    const float mu = S1 / rs;
    float vraw = fmaf(mu * mu, S0, fmaf(-2.f * mu, S1, S2));
    vraw = fmaxf(vraw, 0.f);
    const float var = vraw / rs + EPSF;
    const float lv = __logf(var);
    float sv = lv;
    #pragma unroll
    for (int off = 8; off >= 1; off >>= 1) sv += __shfl_xor(sv, off, 16);
    const float cost = rs * fmaf(0.5f, sv, 16.f * beta_u[o]);
    const float av = 1.f / (1.f + __expf(-inv_temp * (beta_a[o] - cost)));
    if (!final_it) {
        muOut[((size_t)b * OO + o) * 16 + d] = mu;
        ivOut[((size_t)b * OO + o) * 16 + d] = 1.f / var;
        if (d == 0) biOut[b * OO + o] = __logf(av + EPSF) - 0.5f * sv;
    } else {
        out[((size_t)b * OO + o) * 16 + d] = mu;               // pose_out (B,O,16)
        if (d == 0) out[BB * OO * 16 + b * OO + o] = av;       // act_out (B,O)
    }
}

extern "C" void kernel_launch(void* const* d_in, const int* in_sizes, int n_in,
                              void* d_out, int out_size, void* d_ws, size_t ws_size,
                              hipStream_t stream) {
    const float* pose   = (const float*)d_in[0];
    const float* actv   = (const float*)d_in[1];
    const float* wgt    = (const float*)d_in[2];
    const float* beta_a = (const float*)d_in[3];
    const float* beta_u = (const float*)d_in[4];
    float* out = (float*)d_out;
    float* ws  = (float*)d_ws;

    hipMemsetAsync(ws + OFF_ACC, 0, (size_t)3 * ACC_PER_IT * sizeof(float), stream);

    float* acc0 = ws + OFF_ACC;
    float* acc1 = ws + OFF_ACC + ACC_PER_IT;
    float* acc2 = ws + OFF_ACC + 2 * ACC_PER_IT;
    float* mu0 = ws + OFF_MU;            float* mu1 = ws + OFF_MU + 10240;
    float* iv0 = ws + OFF_IV;            float* iv1 = ws + OFF_IV + 10240;
    float* bi0 = ws + OFF_BI;            float* bi1 = ws + OFF_BI + 640;

    dim3 pgrid(SSL, BB), pblk(TPB);
    fc_pass<<<pgrid, pblk, 0, stream>>>(pose, actv, wgt, nullptr, nullptr, nullptr, acc0, 0);
    fc_stats<<<BB, 256, 0, stream>>>(acc0, beta_a, beta_u, mu0, iv0, bi0, out, 1.0f, 0);
    fc_pass<<<pgrid, pblk, 0, stream>>>(pose, actv, wgt, mu0, iv0, bi0, acc1, 1);
    fc_stats<<<BB, 256, 0, stream>>>(acc1, beta_a, beta_u, mu1, iv1, bi1, out, 2.0f, 0);
    fc_pass<<<pgrid, pblk, 0, stream>>>(pose, actv, wgt, mu1, iv1, bi1, acc2, 2);
    fc_stats<<<BB, 256, 0, stream>>>(acc2, beta_a, beta_u, nullptr, nullptr, nullptr, out, 3.0f, 1);
}